// Round 8
// baseline (1018.475 us; speedup 1.0000x reference)
//
#include <hip/hip_runtime.h>
#include <stdint.h>

using bf16x8 = __attribute__((ext_vector_type(8))) __bf16;
using f32x4  = __attribute__((ext_vector_type(4))) float;
using u32x4  = __attribute__((ext_vector_type(4))) unsigned;

#define GLL(g, l) __builtin_amdgcn_global_load_lds(                                  \
    (const __attribute__((address_space(1))) void*)(g),                              \
    (__attribute__((address_space(3))) void*)(l), 16, 0, 0)

__device__ __forceinline__ unsigned short f2bf(float f) {
  unsigned u = __builtin_bit_cast(unsigned, f);
  u += 0x7FFF + ((u >> 16) & 1);   // RNE
  return (unsigned short)(u >> 16);
}
__device__ __forceinline__ float bf2f(unsigned short u) {
  unsigned v = ((unsigned)u) << 16;
  return __builtin_bit_cast(float, v);
}

// ---------------- LDS union: attn (64KB) dominates ----------------
struct SMAttn { unsigned short Ks[2][64 * 128]; unsigned short Vs[2][128 * 64]; };
struct SMGemm { unsigned short As[128 * 64]; unsigned short Bs[128 * 64]; };
union SMem {
  SMAttn a;                    // 64 KB
  SMGemm g;                    // 32 KB
  float T[64][65];             // 16.25 KB
  unsigned short Tv[64][68];   // 8.5 KB
};

// ---------------- device-scope grid barrier (512 blocks) ----------------
// Release: thread0 __threadfence() -> writer-XCD L2 writeback (all block's waves'
// stores already at L2 via the pre-barrier s_waitcnt in __syncthreads).
// Acquire: spin-load ACQUIRE + post-barrier all-thread fence -> reader L1/L2 inv.
__device__ __forceinline__ void gridbar(unsigned* bar) {
  __syncthreads();
  if (threadIdx.x == 0) {
    __threadfence();
    unsigned* cnt = bar;
    unsigned* gen = bar + 1;
    unsigned g = __hip_atomic_load(gen, __ATOMIC_RELAXED, __HIP_MEMORY_SCOPE_AGENT);
    unsigned a = __hip_atomic_fetch_add(cnt, 1u, __ATOMIC_ACQ_REL, __HIP_MEMORY_SCOPE_AGENT);
    if (a == 511u) {
      __hip_atomic_store(cnt, 0u, __ATOMIC_RELAXED, __HIP_MEMORY_SCOPE_AGENT);
      __hip_atomic_fetch_add(gen, 1u, __ATOMIC_ACQ_REL, __HIP_MEMORY_SCOPE_AGENT);
    } else {
      while (__hip_atomic_load(gen, __ATOMIC_ACQUIRE, __HIP_MEMORY_SCOPE_AGENT) == g)
        __builtin_amdgcn_s_sleep(2);
    }
  }
  __syncthreads();
  __threadfence();
}

// ---------------- stage unit bodies (verbatim from verified kernels) ----------------
__device__ __forceinline__ void tcast_unit(const float* __restrict__ W,
                                           unsigned short* __restrict__ Wt,
                                           int K, int N, int kb, int nb,
                                           float (*T)[65]) {
  const int t = threadIdx.x;
  const int k0 = kb * 64, n0 = nb * 64;
  const int r4 = t >> 6, c = t & 63;
#pragma unroll
  for (int p = 0; p < 16; ++p) {
    int r = p * 4 + r4;
    T[r][c] = W[(size_t)(k0 + r) * N + n0 + c];
  }
  __syncthreads();
#pragma unroll
  for (int p = 0; p < 16; ++p) {
    int r = p * 4 + r4;
    Wt[(size_t)(n0 + r) * K + k0 + c] = f2bf(T[c][r]);
  }
  __syncthreads();   // protect T reuse by next grid-stride unit
}

__device__ __forceinline__ void tv_unit(const unsigned short* __restrict__ V,
                                        unsigned short* __restrict__ Vt,
                                        int t0, int d0, unsigned short (*T)[68]) {
  const int t = threadIdx.x;
  const int r4 = t >> 6, c = t & 63;
#pragma unroll
  for (int p = 0; p < 16; ++p) {
    int r = p * 4 + r4;
    T[r][c] = V[(size_t)(t0 + r) * 2560 + 2304 + d0 + c];
  }
  __syncthreads();
  const int b = t0 >> 11;
  const int tl = t0 & 2047;
#pragma unroll
  for (int p = 0; p < 16; ++p) {
    int dr = p * 4 + r4;
    int dg = d0 + dr;
    int g = dg >> 7, dl = dg & 127;
    Vt[(size_t)((b * 2 + g) * 128 + dl) * 2048 + tl + c] = T[c][dr];
  }
  __syncthreads();   // protect T reuse by next grid-stride unit
}

template <bool FP32OUT>
__device__ __forceinline__ void gemm_unit(const unsigned short* __restrict__ A,
                                          const unsigned short* __restrict__ Bt,
                                          void* __restrict__ Cout,
                                          int m0, int n0, int K, int lda, int ldb, int ldc,
                                          float scale, int nscale,
                                          unsigned short* As, unsigned short* Bs) {
  const int t = threadIdx.x;
  const int w = t >> 6, lane = t & 63;
  const int l15 = lane & 15, quad = lane >> 4;
  const int wm = (w >> 1) * 64, wn = (w & 1) * 64;

  const int srow = lane >> 3;
  const int sgl = (lane & 7) ^ srow;

  f32x4 acc[4][4] = {};

  for (int k0 = 0; k0 < K; k0 += 64) {
    __syncthreads();
#pragma unroll
    for (int p = 0; p < 4; ++p) {
      int rowbase = p * 32 + w * 8;
      GLL(&A[(size_t)(m0 + rowbase + srow) * lda + k0 + sgl * 8], &As[rowbase * 64]);
      GLL(&Bt[(size_t)(n0 + rowbase + srow) * ldb + k0 + sgl * 8], &Bs[rowbase * 64]);
    }
    __syncthreads();
#pragma unroll
    for (int kk = 0; kk < 64; kk += 32) {
      const int kg = kk >> 3;
      const int phys = ((kg + quad) ^ (l15 & 7)) * 8;
      bf16x8 af[4], bfr[4];
#pragma unroll
      for (int mt = 0; mt < 4; ++mt)
        af[mt] = *reinterpret_cast<const bf16x8*>(&As[(wm + mt * 16 + l15) * 64 + phys]);
#pragma unroll
      for (int nt = 0; nt < 4; ++nt)
        bfr[nt] = *reinterpret_cast<const bf16x8*>(&Bs[(wn + nt * 16 + l15) * 64 + phys]);
#pragma unroll
      for (int mt = 0; mt < 4; ++mt)
#pragma unroll
        for (int nt = 0; nt < 4; ++nt)
          acc[mt][nt] = __builtin_amdgcn_mfma_f32_16x16x32_bf16(af[mt], bfr[nt], acc[mt][nt], 0, 0, 0);
    }
  }

  const float sc = (n0 < nscale) ? scale : 1.0f;
#pragma unroll
  for (int mt = 0; mt < 4; ++mt) {
#pragma unroll
    for (int reg = 0; reg < 4; ++reg) {
      int row = m0 + wm + mt * 16 + quad * 4 + reg;
#pragma unroll
      for (int nt = 0; nt < 4; ++nt) {
        int col = n0 + wn + nt * 16 + l15;
        float v = acc[mt][nt][reg] * sc;
        if (FP32OUT)
          reinterpret_cast<float*>(Cout)[(size_t)row * ldc + col] = v;
        else
          reinterpret_cast<unsigned short*>(Cout)[(size_t)row * ldc + col] = f2bf(v);
      }
    }
  }
  __syncthreads();   // drain LDS reads before next unit's GLL overwrite
}

// R1-verified parity-split attention block (17 slots), T12 in-register softmax.
#define LDQK 2560
__device__ __forceinline__ void attn_unit(const unsigned short* __restrict__ Q,
                                          const unsigned short* __restrict__ Kg,
                                          const unsigned short* __restrict__ Vt,
                                          float* __restrict__ O0,
                                          unsigned short* __restrict__ O1,
                                          float* __restrict__ L,
                                          int s, int bx, int bh, SMAttn* sm) {
  const int hh = bh & 15;
  const int b  = bh >> 4;
  const int g  = hh >> 3;
  const int t  = threadIdx.x;
  const int wg = t >> 6, lane = t & 63;
  const int l15 = lane & 15, quad = lane >> 4;

  const unsigned short* Kbase = Kg + (size_t)b * 2048 * LDQK + g * 128;
  const unsigned short* Vbase = Vt + (size_t)(b * 2 + g) * 128 * 2048;

  const int k_r = lane >> 4;
  const int v_r = lane >> 3;

  auto issueK = [&](int tile, unsigned short* dst) {
    const unsigned short* kb = Kbase + (size_t)(tile * 64) * LDQK;
#pragma unroll
    for (int p = 0; p < 4; ++p) {
      int rowbase = p * 16 + wg * 4;
      int row = rowbase + k_r;
      int gl = (lane & 15) ^ (row & 15);
      GLL(&kb[(size_t)row * LDQK + gl * 8], &dst[rowbase * 128]);
    }
  };
  auto issueV = [&](int tile, unsigned short* dst) {
    const unsigned short* vb = Vbase + tile * 64;
#pragma unroll
    for (int p = 0; p < 4; ++p) {
      int rowbase = p * 32 + wg * 8;
      int row = rowbase + v_r;
      int gl = (lane & 7) ^ (row & 7);
      GLL(&vb[(size_t)row * 2048 + gl * 8], &dst[rowbase * 64]);
    }
  };

  int pb = 0;
  issueK(s, sm->Ks[0]);
  issueV(s, sm->Vs[0]);

  for (int ph = 0; ph < 2; ++ph) {
    const int iq = ph ? (15 - bx) : bx;

    bf16x8 qf[2][4];
#pragma unroll
    for (int mi = 0; mi < 2; ++mi) {
      int qrow = iq * 128 + wg * 32 + mi * 16 + l15;
      const unsigned short* qp = &Q[(size_t)(b * 2048 + qrow) * LDQK + hh * 128 + quad * 8];
#pragma unroll
      for (int dk = 0; dk < 4; ++dk)
        qf[mi][dk] = *reinterpret_cast<const bf16x8*>(qp + dk * 32);
    }

    f32x4 o[2][8] = {};
    float l_run[2] = {};

    for (int j = 0; j <= iq; ++j) {
      const int tile = 2 * j + s;
      __syncthreads();   // drains GLLs issued last slot; fences buffer reuse
      const int cur = pb, nxt = pb ^ 1;

      if (j < iq) {
        issueK(tile + 2, sm->Ks[nxt]);
        issueV(tile + 2, sm->Vs[nxt]);
      } else if (ph == 0) {
        issueK(s, sm->Ks[nxt]);
        issueV(s, sm->Vs[nxt]);
      }

      // S^T = K Q^T (swapped operands: row = k-token, col = q-row = l15)
      f32x4 sc[2][4] = {};
#pragma unroll
      for (int nt = 0; nt < 4; ++nt) {
#pragma unroll
        for (int dk = 0; dk < 4; ++dk) {
          int phys = (dk * 4 + quad) ^ l15;
          bf16x8 kf = *reinterpret_cast<const bf16x8*>(&sm->Ks[cur][(nt * 16 + l15) * 128 + phys * 8]);
          sc[0][nt] = __builtin_amdgcn_mfma_f32_16x16x32_bf16(kf, qf[0][dk], sc[0][nt], 0, 0, 0);
          sc[1][nt] = __builtin_amdgcn_mfma_f32_16x16x32_bf16(kf, qf[1][dk], sc[1][nt], 0, 0, 0);
        }
      }
      if (j == iq) {   // last tile of this parity stream: causal mask (S^T indexing)
#pragma unroll
        for (int mi = 0; mi < 2; ++mi)
#pragma unroll
          for (int nt = 0; nt < 4; ++nt) {
#pragma unroll
            for (int reg = 0; reg < 4; ++reg) {
              int kcol = tile * 64 + nt * 16 + quad * 4 + reg;
              int qr = iq * 128 + wg * 32 + mi * 16 + l15;
              if (kcol > qr) sc[mi][nt][reg] = -1e30f;
            }
          }
      }

      // two 32-token halves: softmax + in-register P fragment -> PV
#pragma unroll
      for (int kk = 0; kk < 2; ++kk) {
        bf16x8 pf[2];
#pragma unroll
        for (int mi = 0; mi < 2; ++mi) {
          float pe[4], po[4];
#pragma unroll
          for (int reg = 0; reg < 4; ++reg) {
            pe[reg] = __builtin_exp2f(__builtin_fmaf(sc[mi][kk * 2 + 0][reg], 1.44269504f, -23.08312064f));
            po[reg] = __builtin_exp2f(__builtin_fmaf(sc[mi][kk * 2 + 1][reg], 1.44269504f, -23.08312064f));
            l_run[mi] += pe[reg] + po[reg];
          }
          unsigned a0, a1, b0, b1;
          asm("v_cvt_pk_bf16_f32 %0, %1, %2" : "=v"(a0) : "v"(pe[0]), "v"(pe[1]));
          asm("v_cvt_pk_bf16_f32 %0, %1, %2" : "=v"(a1) : "v"(pe[2]), "v"(pe[3]));
          asm("v_cvt_pk_bf16_f32 %0, %1, %2" : "=v"(b0) : "v"(po[0]), "v"(po[1]));
          asm("v_cvt_pk_bf16_f32 %0, %1, %2" : "=v"(b1) : "v"(po[2]), "v"(po[3]));
          asm("v_permlane32_swap_b32 %0, %1" : "+v"(a0), "+v"(b0));
          asm("v_permlane16_swap_b32 %0, %1" : "+v"(a0), "+v"(b0));
          asm("v_permlane32_swap_b32 %0, %1" : "+v"(a1), "+v"(b1));
          asm("v_permlane16_swap_b32 %0, %1" : "+v"(a1), "+v"(b1));
          u32x4 wd;
          wd[0] = a0;   // tokens q*8+0,1
          wd[1] = a1;   // tokens q*8+2,3
          wd[2] = b0;   // tokens q*8+4,5
          wd[3] = b1;   // tokens q*8+6,7
          pf[mi] = __builtin_bit_cast(bf16x8, wd);
        }
#pragma unroll
        for (int dt = 0; dt < 8; ++dt) {
          int phys = ((kk * 4 + quad) ^ (l15 & 7));
          bf16x8 vf = *reinterpret_cast<const bf16x8*>(&sm->Vs[cur][(dt * 16 + l15) * 64 + phys * 8]);
          o[0][dt] = __builtin_amdgcn_mfma_f32_16x16x32_bf16(pf[0], vf, o[0][dt], 0, 0, 0);
          o[1][dt] = __builtin_amdgcn_mfma_f32_16x16x32_bf16(pf[1], vf, o[1][dt], 0, 0, 0);
        }
      }
      pb ^= 1;
    }

    // l lives per (qrow=l15, quad-partial): reduce across quads
#pragma unroll
    for (int mi = 0; mi < 2; ++mi) {
      l_run[mi] += __shfl_xor(l_run[mi], 16);
      l_run[mi] += __shfl_xor(l_run[mi], 32);
    }

#pragma unroll
    for (int mi = 0; mi < 2; ++mi) {
      if (quad == 0) {
        int lrow = wg * 32 + mi * 16 + l15;
        L[(size_t)s * 65536 + (size_t)(b * 2048 + iq * 128 + lrow) * 16 + hh] = l_run[mi];
      }
#pragma unroll
      for (int reg = 0; reg < 4; ++reg) {
        int row = wg * 32 + mi * 16 + quad * 4 + reg;
        size_t base = (size_t)(b * 2048 + iq * 128 + row) * 2048 + hh * 128;
        if (s == 0) {
#pragma unroll
          for (int dt = 0; dt < 8; ++dt)
            O0[base + dt * 16 + l15] = o[mi][dt][reg];
        } else {
#pragma unroll
          for (int dt = 0; dt < 8; ++dt)
            O1[base + dt * 16 + l15] = f2bf(o[mi][dt][reg]);
        }
      }
    }
  }
  __syncthreads();   // drain before LDS reuse by later stages
}

__device__ __forceinline__ void merge_unit(const float* __restrict__ O0,
                                           unsigned short* __restrict__ O1,
                                           const float* __restrict__ L, int i4) {
  int e = i4 << 2;
  int tr = e >> 11;              // token row 0..4095
  int hh = (e >> 7) & 15;        // head
  float l = L[tr * 16 + hh] + L[65536 + tr * 16 + hh];
  float inv = 1.0f / l;
  float4 a = reinterpret_cast<const float4*>(O0)[i4];
  ushort4 u = reinterpret_cast<const ushort4*>(O1)[i4];
  ushort4 r;
  r.x = f2bf((a.x + bf2f(u.x)) * inv);
  r.y = f2bf((a.y + bf2f(u.y)) * inv);
  r.z = f2bf((a.z + bf2f(u.z)) * inv);
  r.w = f2bf((a.w + bf2f(u.w)) * inv);
  reinterpret_cast<ushort4*>(O1)[i4] = r;
}

// ---------------- persistent mega kernel: 512 blocks, 6 stages, 5 grid barriers ----------------
__global__ __launch_bounds__(256, 2) void mega_kernel(const float* __restrict__ x,
                                                      const float* __restrict__ Wq,
                                                      const float* __restrict__ Wk,
                                                      const float* __restrict__ Wv,
                                                      const float* __restrict__ Wo,
                                                      unsigned short* __restrict__ xb,
                                                      unsigned short* __restrict__ Wqkvt,
                                                      unsigned short* __restrict__ Wot,
                                                      unsigned short* __restrict__ QKVb,
                                                      unsigned short* __restrict__ Vtb,
                                                      float* __restrict__ O0s,
                                                      unsigned short* __restrict__ Yb,
                                                      float* __restrict__ Lb,
                                                      float* __restrict__ outp,
                                                      unsigned* __restrict__ bar) {
  __shared__ __align__(16) SMem sm;
  const int bid = blockIdx.x;
  const int t = threadIdx.x;
  const float qscale = 0.08838834764831845f;   // 1/sqrt(128), folded into Q

  // S0: prep (cast x, transpose+cast weights) -- 10496 units
  for (int u = bid; u < 10496; u += 512) {
    if (u < 8192) {
      int i = u * 256 + t;
      float4 v = reinterpret_cast<const float4*>(x)[i];
      ushort4 o;
      o.x = f2bf(v.x); o.y = f2bf(v.y); o.z = f2bf(v.z); o.w = f2bf(v.w);
      reinterpret_cast<ushort4*>(xb)[i] = o;
    } else {
      int v2 = u - 8192;
      if (v2 < 1024)       tcast_unit(Wq, Wqkvt, 2048, 2048, v2 & 31, v2 >> 5, sm.T);
      else if (v2 < 1152) { int v3 = v2 - 1024; tcast_unit(Wk, Wqkvt + (size_t)2048 * 2048, 2048, 256, v3 & 31, v3 >> 5, sm.T); }
      else if (v2 < 1280) { int v3 = v2 - 1152; tcast_unit(Wv, Wqkvt + (size_t)2304 * 2048, 2048, 256, v3 & 31, v3 >> 5, sm.T); }
      else                { int v3 = v2 - 1280; tcast_unit(Wo, Wot, 2048, 2048, v3 & 31, v3 >> 5, sm.T); }
    }
  }
  gridbar(bar);

  // S1: QKV projection gemm -- 640 units (dim3(32,20) linearization)
  for (int u = bid; u < 640; u += 512)
    gemm_unit<false>(xb, Wqkvt, QKVb, (u & 31) * 128, (u >> 5) * 128,
                     2048, 2048, 2048, 2560, qscale, 2048, sm.g.As, sm.g.Bs);
  gridbar(bar);

  // S2: V transpose -- 256 units (dim3(64,4) linearization)
  for (int u = bid; u < 256; u += 512)
    tv_unit(QKVb, Vtb, (u & 63) * 64, (u >> 6) * 64, sm.Tv);
  gridbar(bar);

  // S3: attention -- 512 units, 1:1 (dim3(2,8,32) linearization)
  attn_unit(QKVb, QKVb + 2048, Vtb, O0s, Yb, Lb, bid & 1, (bid >> 1) & 7, bid >> 4, &sm.a);
  gridbar(bar);

  // S4: merge -- 8192 units
  for (int u = bid; u < 8192; u += 512)
    merge_unit(O0s, Yb, Lb, u * 256 + t);
  gridbar(bar);

  // S5: output projection gemm -- 512 units, 1:1 (dim3(32,16) linearization)
  gemm_unit<true>(Yb, Wot, outp, (bid & 31) * 128, (bid >> 5) * 128,
                  2048, 2048, 2048, 2048, 1.0f, 0, sm.g.As, sm.g.Bs);
}

extern "C" void kernel_launch(void* const* d_in, const int* in_sizes, int n_in,
                              void* d_out, int out_size, void* d_ws, size_t ws_size,
                              hipStream_t stream) {
  const float* x  = (const float*)d_in[0];
  const float* Wq = (const float*)d_in[1];
  const float* Wk = (const float*)d_in[2];
  const float* Wv = (const float*)d_in[3];
  const float* Wo = (const float*)d_in[4];

  char* ws = (char*)d_ws;
  unsigned short* xb    = (unsigned short*)(ws + 0);          // 16 MB (reused: O1/Y)
  unsigned short* Wqkvt = (unsigned short*)(ws + 16777216);   // 10.5 MB
  unsigned short* Wot   = (unsigned short*)(ws + 27262976);   // 8 MB
  unsigned short* QKVb  = (unsigned short*)(ws + 35651584);   // 20 MB
  unsigned short* Vtb   = (unsigned short*)(ws + 56623104);   // 2 MB
  float*          Lb    = (float*)(ws + 58720256);            // 512 KB: [2][4096][16]
  unsigned*       bar   = (unsigned*)(ws + 59244544);         // 8 B: {cnt, gen}
  unsigned short* Yb    = xb;

  hipMemsetAsync(bar, 0, 8, stream);
  mega_kernel<<<512, 256, 0, stream>>>(x, Wq, Wk, Wv, Wo, xb, Wqkvt, Wot,
                                       QKVb, Vtb, (float*)d_out, Yb, Lb,
                                       (float*)d_out, bar);
}

// Round 9
// 274.563 us; speedup vs baseline: 3.7094x; 3.7094x over previous
//
#include <hip/hip_runtime.h>
#include <stdint.h>

using bf16x8 = __attribute__((ext_vector_type(8))) __bf16;
using f32x4  = __attribute__((ext_vector_type(4))) float;
using u32x4  = __attribute__((ext_vector_type(4))) unsigned;

#define GLL(g, l) __builtin_amdgcn_global_load_lds(                                  \
    (const __attribute__((address_space(1))) void*)(g),                              \
    (__attribute__((address_space(3))) void*)(l), 16, 0, 0)

__device__ __forceinline__ unsigned short f2bf(float f) {
  unsigned u = __builtin_bit_cast(unsigned, f);
  u += 0x7FFF + ((u >> 16) & 1);   // RNE
  return (unsigned short)(u >> 16);
}
__device__ __forceinline__ float bf2f(unsigned short u) {
  unsigned v = ((unsigned)u) << 16;
  return __builtin_bit_cast(float, v);
}

// ---------- fused prep: cast x -> bf16, transpose+cast 4 weight matrices ----------
__device__ __forceinline__ void tcast_block(const float* __restrict__ W,
                                            unsigned short* __restrict__ Wt,
                                            int K, int N, int kb, int nb,
                                            float (*T)[65], int t) {
  const int k0 = kb * 64, n0 = nb * 64;
  const int r4 = t >> 6, c = t & 63;
#pragma unroll
  for (int p = 0; p < 16; ++p) {
    int r = p * 4 + r4;
    T[r][c] = W[(size_t)(k0 + r) * N + n0 + c];
  }
  __syncthreads();
#pragma unroll
  for (int p = 0; p < 16; ++p) {
    int r = p * 4 + r4;
    Wt[(size_t)(n0 + r) * K + k0 + c] = f2bf(T[c][r]);
  }
}

__global__ __launch_bounds__(256) void prep_kernel(const float* __restrict__ x,
                                                   const float* __restrict__ Wq,
                                                   const float* __restrict__ Wk,
                                                   const float* __restrict__ Wv,
                                                   const float* __restrict__ Wo,
                                                   unsigned short* __restrict__ xb,
                                                   unsigned short* __restrict__ Wqkvt,
                                                   unsigned short* __restrict__ Wot) {
  __shared__ float T[64][65];
  int bid = blockIdx.x;
  const int t = threadIdx.x;
  if (bid < 8192) {
    int i = bid * 256 + t;
    float4 v = reinterpret_cast<const float4*>(x)[i];
    ushort4 o;
    o.x = f2bf(v.x); o.y = f2bf(v.y); o.z = f2bf(v.z); o.w = f2bf(v.w);
    reinterpret_cast<ushort4*>(xb)[i] = o;
    return;
  }
  bid -= 8192;
  if (bid < 1024) { tcast_block(Wq, Wqkvt, 2048, 2048, bid & 31, bid >> 5, T, t); return; }
  bid -= 1024;
  if (bid < 128)  { tcast_block(Wk, Wqkvt + (size_t)2048 * 2048, 2048, 256, bid & 31, bid >> 5, T, t); return; }
  bid -= 128;
  if (bid < 128)  { tcast_block(Wv, Wqkvt + (size_t)2304 * 2048, 2048, 256, bid & 31, bid >> 5, T, t); return; }
  bid -= 128;
  tcast_block(Wo, Wot, 2048, 2048, bid & 31, bid >> 5, T, t);
}

// ---------- GEMM: C[M][N] = A[M][K] * Bt[N][K]^T (m97-style) ----------
// TVOUT: for V column-blocks (n0 >= 2304), route the tile through an LDS
// transpose (reusing As/Bs as a [128][128] bf16 scratch, XOR-swizzled) and
// store COALESCED ushort2 along the token axis into Vt -- replaces tv_kernel.
// (R7's direct scattered-store variant was correct but 16x store-issue bound.)
template <bool FP32OUT, bool TVOUT>
__global__ __launch_bounds__(256) void gemm_bt_kernel(const unsigned short* __restrict__ A,
                                                      const unsigned short* __restrict__ Bt,
                                                      void* __restrict__ Cout,
                                                      unsigned short* __restrict__ Vt,
                                                      int K, int lda, int ldb, int ldc,
                                                      float scale, int nscale) {
  __shared__ __align__(16) unsigned short S[128 * 128];   // As | Bs ; reused as Ts
  unsigned short* As = S;
  unsigned short* Bs = S + 128 * 64;
  const int m0 = blockIdx.x * 128, n0 = blockIdx.y * 128;
  const int t = threadIdx.x;
  const int w = t >> 6, lane = t & 63;
  const int l15 = lane & 15, quad = lane >> 4;
  const int wm = (w >> 1) * 64, wn = (w & 1) * 64;

  const int srow = lane >> 3;
  const int sgl = (lane & 7) ^ srow;

  f32x4 acc[4][4] = {};

  for (int k0 = 0; k0 < K; k0 += 64) {
    __syncthreads();
#pragma unroll
    for (int p = 0; p < 4; ++p) {
      int rowbase = p * 32 + w * 8;
      GLL(&A[(size_t)(m0 + rowbase + srow) * lda + k0 + sgl * 8], &As[rowbase * 64]);
      GLL(&Bt[(size_t)(n0 + rowbase + srow) * ldb + k0 + sgl * 8], &Bs[rowbase * 64]);
    }
    __syncthreads();
#pragma unroll
    for (int kk = 0; kk < 64; kk += 32) {
      const int kg = kk >> 3;
      const int phys = ((kg + quad) ^ (l15 & 7)) * 8;
      bf16x8 af[4], bfr[4];
#pragma unroll
      for (int mt = 0; mt < 4; ++mt)
        af[mt] = *reinterpret_cast<const bf16x8*>(&As[(wm + mt * 16 + l15) * 64 + phys]);
#pragma unroll
      for (int nt = 0; nt < 4; ++nt)
        bfr[nt] = *reinterpret_cast<const bf16x8*>(&Bs[(wn + nt * 16 + l15) * 64 + phys]);
#pragma unroll
      for (int mt = 0; mt < 4; ++mt)
#pragma unroll
        for (int nt = 0; nt < 4; ++nt)
          acc[mt][nt] = __builtin_amdgcn_mfma_f32_16x16x32_bf16(af[mt], bfr[nt], acc[mt][nt], 0, 0, 0);
    }
  }

  if (TVOUT && n0 >= 2304) {   // V tile -> LDS transpose -> coalesced Vt store
    __syncthreads();           // main-loop LDS reads done before scratch reuse
    const int gg = (n0 - 2304) >> 7;      // block-uniform: 0 or 1
    // write phase: Ts[col][row ^ ((col&31)<<1)] = bf16(acc), col=dv, row=token
#pragma unroll
    for (int mt = 0; mt < 4; ++mt) {
#pragma unroll
      for (int reg = 0; reg < 4; ++reg) {
        int row = wm + mt * 16 + quad * 4 + reg;
#pragma unroll
        for (int nt = 0; nt < 4; ++nt) {
          int col = wn + nt * 16 + l15;
          S[col * 128 + (row ^ ((col & 31) << 1))] = f2bf(acc[mt][nt][reg]);
        }
      }
    }
    __syncthreads();
    // read+store phase: wave w handles dv = p*4+w; lane c -> token pair 2c,2c+1
    const int bb = m0 >> 11;
    const int tl0 = m0 & 2047;
    const int c2 = t & 63, wv = t >> 6;
#pragma unroll
    for (int p = 0; p < 32; ++p) {
      int dvl = p * 4 + wv;
      int rsw = (2 * c2) ^ ((dvl & 31) << 1);   // even -> {row 2c, row 2c+1} adjacent
      unsigned pair = *reinterpret_cast<const unsigned*>(&S[dvl * 128 + rsw]);
      *reinterpret_cast<unsigned*>(
          &Vt[(size_t)((bb * 2 + gg) * 128 + dvl) * 2048 + tl0 + 2 * c2]) = pair;
    }
    return;
  }

  const float sc = (n0 < nscale) ? scale : 1.0f;
#pragma unroll
  for (int mt = 0; mt < 4; ++mt) {
#pragma unroll
    for (int reg = 0; reg < 4; ++reg) {
      int row = m0 + wm + mt * 16 + quad * 4 + reg;
#pragma unroll
      for (int nt = 0; nt < 4; ++nt) {
        int col = n0 + wn + nt * 16 + l15;
        float v = acc[mt][nt][reg] * sc;
        if (FP32OUT)
          reinterpret_cast<float*>(Cout)[(size_t)row * ldc + col] = v;
        else
          reinterpret_cast<unsigned short*>(Cout)[(size_t)row * ldc + col] = f2bf(v);
      }
    }
  }
}

// ---------- fused causal GQA flash attention, k-parity split (R1-verified) ----------
// grid (2, 8, 32): block (s,bx,bh) handles q-tiles {bx, 15-bx} (128 rows each)
// processing only K/V tiles of parity s -> EXACTLY 17 slots per block (caps the
// max serial block length -- the parity split's purpose).
// T12 in-register softmax (swapped QK^T + cvt_pk + permlane); no setprio.
#define LDQK 2560
__global__ __launch_bounds__(256, 2) void attn_kernel(const unsigned short* __restrict__ Q,
                                                      const unsigned short* __restrict__ Kg,
                                                      const unsigned short* __restrict__ Vt,
                                                      float* __restrict__ O0,
                                                      unsigned short* __restrict__ O1,
                                                      float* __restrict__ L) {
  __shared__ __align__(16) unsigned short Ks[2][64 * 128];   // [token][d], swizzled
  __shared__ __align__(16) unsigned short Vs[2][128 * 64];   // [d][token], swizzled

  const int s  = blockIdx.x;            // k-parity
  const int bx = blockIdx.y;            // 0..7
  const int hh = blockIdx.z & 15;
  const int b  = blockIdx.z >> 4;
  const int g  = hh >> 3;
  const int t  = threadIdx.x;
  const int wg = t >> 6, lane = t & 63;
  const int l15 = lane & 15, quad = lane >> 4;

  const unsigned short* Kbase = Kg + (size_t)b * 2048 * LDQK + g * 128;
  const unsigned short* Vbase = Vt + (size_t)(b * 2 + g) * 128 * 2048;

  const int k_r = lane >> 4;
  const int v_r = lane >> 3;

  auto issueK = [&](int tile, unsigned short* dst) {
    const unsigned short* kb = Kbase + (size_t)(tile * 64) * LDQK;
#pragma unroll
    for (int p = 0; p < 4; ++p) {
      int rowbase = p * 16 + wg * 4;
      int row = rowbase + k_r;
      int gl = (lane & 15) ^ (row & 15);
      GLL(&kb[(size_t)row * LDQK + gl * 8], &dst[rowbase * 128]);
    }
  };
  auto issueV = [&](int tile, unsigned short* dst) {
    const unsigned short* vb = Vbase + tile * 64;
#pragma unroll
    for (int p = 0; p < 4; ++p) {
      int rowbase = p * 32 + wg * 8;
      int row = rowbase + v_r;
      int gl = (lane & 7) ^ (row & 7);
      GLL(&vb[(size_t)row * 2048 + gl * 8], &dst[rowbase * 64]);
    }
  };

  int pb = 0;
  issueK(s, Ks[0]);
  issueV(s, Vs[0]);

  for (int ph = 0; ph < 2; ++ph) {
    const int iq = ph ? (15 - bx) : bx;

    bf16x8 qf[2][4];
#pragma unroll
    for (int mi = 0; mi < 2; ++mi) {
      int qrow = iq * 128 + wg * 32 + mi * 16 + l15;
      const unsigned short* qp = &Q[(size_t)(b * 2048 + qrow) * LDQK + hh * 128 + quad * 8];
#pragma unroll
      for (int dk = 0; dk < 4; ++dk)
        qf[mi][dk] = *reinterpret_cast<const bf16x8*>(qp + dk * 32);
    }

    f32x4 o[2][8] = {};
    float l_run[2] = {};

    for (int j = 0; j <= iq; ++j) {
      const int tile = 2 * j + s;
      __syncthreads();   // drains GLLs issued last slot; fences buffer reuse
      const int cur = pb, nxt = pb ^ 1;

      if (j < iq) {
        issueK(tile + 2, Ks[nxt]);
        issueV(tile + 2, Vs[nxt]);
      } else if (ph == 0) {
        issueK(s, Ks[nxt]);
        issueV(s, Vs[nxt]);
      }

      // S^T = K Q^T (swapped operands: row = k-token, col = q-row = l15)
      f32x4 sc[2][4] = {};
#pragma unroll
      for (int nt = 0; nt < 4; ++nt) {
#pragma unroll
        for (int dk = 0; dk < 4; ++dk) {
          int phys = (dk * 4 + quad) ^ l15;
          bf16x8 kf = *reinterpret_cast<const bf16x8*>(&Ks[cur][(nt * 16 + l15) * 128 + phys * 8]);
          sc[0][nt] = __builtin_amdgcn_mfma_f32_16x16x32_bf16(kf, qf[0][dk], sc[0][nt], 0, 0, 0);
          sc[1][nt] = __builtin_amdgcn_mfma_f32_16x16x32_bf16(kf, qf[1][dk], sc[1][nt], 0, 0, 0);
        }
      }
      if (j == iq) {   // last tile of this parity stream: causal mask (S^T indexing)
#pragma unroll
        for (int mi = 0; mi < 2; ++mi)
#pragma unroll
          for (int nt = 0; nt < 4; ++nt) {
#pragma unroll
            for (int reg = 0; reg < 4; ++reg) {
              int kcol = tile * 64 + nt * 16 + quad * 4 + reg;
              int qr = iq * 128 + wg * 32 + mi * 16 + l15;
              if (kcol > qr) sc[mi][nt][reg] = -1e30f;
            }
          }
      }

      // two 32-token halves: softmax + in-register P fragment -> PV
#pragma unroll
      for (int kk = 0; kk < 2; ++kk) {
        bf16x8 pf[2];
#pragma unroll
        for (int mi = 0; mi < 2; ++mi) {
          float pe[4], po[4];
#pragma unroll
          for (int reg = 0; reg < 4; ++reg) {
            pe[reg] = __builtin_exp2f(__builtin_fmaf(sc[mi][kk * 2 + 0][reg], 1.44269504f, -23.08312064f));
            po[reg] = __builtin_exp2f(__builtin_fmaf(sc[mi][kk * 2 + 1][reg], 1.44269504f, -23.08312064f));
            l_run[mi] += pe[reg] + po[reg];
          }
          unsigned a0, a1, b0, b1;
          asm("v_cvt_pk_bf16_f32 %0, %1, %2" : "=v"(a0) : "v"(pe[0]), "v"(pe[1]));
          asm("v_cvt_pk_bf16_f32 %0, %1, %2" : "=v"(a1) : "v"(pe[2]), "v"(pe[3]));
          asm("v_cvt_pk_bf16_f32 %0, %1, %2" : "=v"(b0) : "v"(po[0]), "v"(po[1]));
          asm("v_cvt_pk_bf16_f32 %0, %1, %2" : "=v"(b1) : "v"(po[2]), "v"(po[3]));
          asm("v_permlane32_swap_b32 %0, %1" : "+v"(a0), "+v"(b0));
          asm("v_permlane16_swap_b32 %0, %1" : "+v"(a0), "+v"(b0));
          asm("v_permlane32_swap_b32 %0, %1" : "+v"(a1), "+v"(b1));
          asm("v_permlane16_swap_b32 %0, %1" : "+v"(a1), "+v"(b1));
          u32x4 wd;
          wd[0] = a0;   // tokens q*8+0,1
          wd[1] = a1;   // tokens q*8+2,3
          wd[2] = b0;   // tokens q*8+4,5
          wd[3] = b1;   // tokens q*8+6,7
          pf[mi] = __builtin_bit_cast(bf16x8, wd);
        }
#pragma unroll
        for (int dt = 0; dt < 8; ++dt) {
          int phys = ((kk * 4 + quad) ^ (l15 & 7));
          bf16x8 vf = *reinterpret_cast<const bf16x8*>(&Vs[cur][(dt * 16 + l15) * 64 + phys * 8]);
          o[0][dt] = __builtin_amdgcn_mfma_f32_16x16x32_bf16(pf[0], vf, o[0][dt], 0, 0, 0);
          o[1][dt] = __builtin_amdgcn_mfma_f32_16x16x32_bf16(pf[1], vf, o[1][dt], 0, 0, 0);
        }
      }
      pb ^= 1;
    }

    // l lives per (qrow=l15, quad-partial): reduce across quads
#pragma unroll
    for (int mi = 0; mi < 2; ++mi) {
      l_run[mi] += __shfl_xor(l_run[mi], 16);
      l_run[mi] += __shfl_xor(l_run[mi], 32);
    }

#pragma unroll
    for (int mi = 0; mi < 2; ++mi) {
      if (quad == 0) {
        int lrow = wg * 32 + mi * 16 + l15;
        L[(size_t)s * 65536 + (size_t)(b * 2048 + iq * 128 + lrow) * 16 + hh] = l_run[mi];
      }
#pragma unroll
      for (int reg = 0; reg < 4; ++reg) {
        int row = wg * 32 + mi * 16 + quad * 4 + reg;
        size_t base = (size_t)(b * 2048 + iq * 128 + row) * 2048 + hh * 128;
        if (s == 0) {
#pragma unroll
          for (int dt = 0; dt < 8; ++dt)
            O0[base + dt * 16 + l15] = o[mi][dt][reg];
        } else {
#pragma unroll
          for (int dt = 0; dt < 8; ++dt)
            O1[base + dt * 16 + l15] = f2bf(o[mi][dt][reg]);
        }
      }
    }
  }
}

// ---------- merge: Y = (O0 + O1) / (l0 + l1), bf16, in-place over O1 ----------
__global__ __launch_bounds__(256) void merge_kernel(const float* __restrict__ O0,
                                                    unsigned short* __restrict__ O1,
                                                    const float* __restrict__ L) {
  int i4 = blockIdx.x * 256 + threadIdx.x;   // 0..2097151, 4 elems each
  int e = i4 << 2;
  int tr = e >> 11;              // token row 0..4095
  int hh = (e >> 7) & 15;        // head
  float l = L[tr * 16 + hh] + L[65536 + tr * 16 + hh];
  float inv = 1.0f / l;
  float4 a = reinterpret_cast<const float4*>(O0)[i4];
  ushort4 u = reinterpret_cast<const ushort4*>(O1)[i4];
  ushort4 r;
  r.x = f2bf((a.x + bf2f(u.x)) * inv);
  r.y = f2bf((a.y + bf2f(u.y)) * inv);
  r.z = f2bf((a.z + bf2f(u.z)) * inv);
  r.w = f2bf((a.w + bf2f(u.w)) * inv);
  reinterpret_cast<ushort4*>(O1)[i4] = r;
}

extern "C" void kernel_launch(void* const* d_in, const int* in_sizes, int n_in,
                              void* d_out, int out_size, void* d_ws, size_t ws_size,
                              hipStream_t stream) {
  const float* x  = (const float*)d_in[0];
  const float* Wq = (const float*)d_in[1];
  const float* Wk = (const float*)d_in[2];
  const float* Wv = (const float*)d_in[3];
  const float* Wo = (const float*)d_in[4];

  char* ws = (char*)d_ws;
  unsigned short* xb    = (unsigned short*)(ws + 0);          // 16 MB (reused: O1/Y)
  unsigned short* Wqkvt = (unsigned short*)(ws + 16777216);   // 10.5 MB
  unsigned short* Wot   = (unsigned short*)(ws + 27262976);   // 8 MB
  unsigned short* QKVb  = (unsigned short*)(ws + 35651584);   // 20 MB
  unsigned short* Vtb   = (unsigned short*)(ws + 56623104);   // 2 MB
  float*          Lb    = (float*)(ws + 58720256);            // 512 KB: [2][4096][16]
  unsigned short* Yb    = xb;

  prep_kernel<<<10496, 256, 0, stream>>>(x, Wq, Wk, Wv, Wo, xb, Wqkvt, Wot);

  const float qscale = 0.08838834764831845f;  // 1/sqrt(128), folded into Q
  // QKV projection; V column-blocks go through LDS transpose into Vtb (tv fused)
  gemm_bt_kernel<false, true><<<dim3(32, 20), 256, 0, stream>>>(xb, Wqkvt, QKVb, Vtb,
                                                                2048, 2048, 2048, 2560,
                                                                qscale, 2048);
  // attention partials: O0 fp32 -> d_out (scratch until final gemm), O1 bf16 -> xb
  attn_kernel<<<dim3(2, 8, 32), 256, 0, stream>>>(QKVb, QKVb + 2048, Vtb,
                                                  (float*)d_out, Yb, Lb);
  merge_kernel<<<8192, 256, 0, stream>>>((const float*)d_out, Yb, Lb);
  gemm_bt_kernel<true, false><<<dim3(32, 16), 256, 0, stream>>>(Yb, Wot, d_out, nullptr,
                                                                2048, 2048, 2048, 2048,
                                                                1.0f, 0);
}

// Round 10
// 269.294 us; speedup vs baseline: 3.7820x; 1.0196x over previous
//
#include <hip/hip_runtime.h>
#include <stdint.h>

using bf16x8 = __attribute__((ext_vector_type(8))) __bf16;
using f32x4  = __attribute__((ext_vector_type(4))) float;
using u32x4  = __attribute__((ext_vector_type(4))) unsigned;

#define GLL(g, l) __builtin_amdgcn_global_load_lds(                                  \
    (const __attribute__((address_space(1))) void*)(g),                              \
    (__attribute__((address_space(3))) void*)(l), 16, 0, 0)

__device__ __forceinline__ unsigned short f2bf(float f) {
  unsigned u = __builtin_bit_cast(unsigned, f);
  u += 0x7FFF + ((u >> 16) & 1);   // RNE
  return (unsigned short)(u >> 16);
}
__device__ __forceinline__ float bf2f(unsigned short u) {
  unsigned v = ((unsigned)u) << 16;
  return __builtin_bit_cast(float, v);
}

// ---------- fused prep: cast x -> bf16, transpose+cast 4 weight matrices ----------
__device__ __forceinline__ void tcast_block(const float* __restrict__ W,
                                            unsigned short* __restrict__ Wt,
                                            int K, int N, int kb, int nb,
                                            float (*T)[65], int t) {
  const int k0 = kb * 64, n0 = nb * 64;
  const int r4 = t >> 6, c = t & 63;
#pragma unroll
  for (int p = 0; p < 16; ++p) {
    int r = p * 4 + r4;
    T[r][c] = W[(size_t)(k0 + r) * N + n0 + c];
  }
  __syncthreads();
#pragma unroll
  for (int p = 0; p < 16; ++p) {
    int r = p * 4 + r4;
    Wt[(size_t)(n0 + r) * K + k0 + c] = f2bf(T[c][r]);
  }
}

__global__ __launch_bounds__(256) void prep_kernel(const float* __restrict__ x,
                                                   const float* __restrict__ Wq,
                                                   const float* __restrict__ Wk,
                                                   const float* __restrict__ Wv,
                                                   const float* __restrict__ Wo,
                                                   unsigned short* __restrict__ xb,
                                                   unsigned short* __restrict__ Wqkvt,
                                                   unsigned short* __restrict__ Wot) {
  __shared__ float T[64][65];
  int bid = blockIdx.x;
  const int t = threadIdx.x;
  if (bid < 8192) {
    int i = bid * 256 + t;
    float4 v = reinterpret_cast<const float4*>(x)[i];
    ushort4 o;
    o.x = f2bf(v.x); o.y = f2bf(v.y); o.z = f2bf(v.z); o.w = f2bf(v.w);
    reinterpret_cast<ushort4*>(xb)[i] = o;
    return;
  }
  bid -= 8192;
  if (bid < 1024) { tcast_block(Wq, Wqkvt, 2048, 2048, bid & 31, bid >> 5, T, t); return; }
  bid -= 1024;
  if (bid < 128)  { tcast_block(Wk, Wqkvt + (size_t)2048 * 2048, 2048, 256, bid & 31, bid >> 5, T, t); return; }
  bid -= 128;
  if (bid < 128)  { tcast_block(Wv, Wqkvt + (size_t)2304 * 2048, 2048, 256, bid & 31, bid >> 5, T, t); return; }
  bid -= 128;
  tcast_block(Wo, Wot, 2048, 2048, bid & 31, bid >> 5, T, t);
}

// ---------- GEMM: C[M][N] = A[M][K] * Bt[N][K]^T (m97-style) ----------
// TVOUT: for V column-blocks (n0 >= 2304), route the tile through an LDS
// transpose (reusing As/Bs as a [128][128] bf16 scratch, XOR-swizzled) and
// store COALESCED ushort2 along the token axis into Vt -- replaces tv_kernel.
template <bool FP32OUT, bool TVOUT>
__global__ __launch_bounds__(256) void gemm_bt_kernel(const unsigned short* __restrict__ A,
                                                      const unsigned short* __restrict__ Bt,
                                                      void* __restrict__ Cout,
                                                      unsigned short* __restrict__ Vt,
                                                      int K, int lda, int ldb, int ldc,
                                                      float scale, int nscale) {
  __shared__ __align__(16) unsigned short S[128 * 128];   // As | Bs ; reused as Ts
  unsigned short* As = S;
  unsigned short* Bs = S + 128 * 64;
  const int m0 = blockIdx.x * 128, n0 = blockIdx.y * 128;
  const int t = threadIdx.x;
  const int w = t >> 6, lane = t & 63;
  const int l15 = lane & 15, quad = lane >> 4;
  const int wm = (w >> 1) * 64, wn = (w & 1) * 64;

  const int srow = lane >> 3;
  const int sgl = (lane & 7) ^ srow;

  f32x4 acc[4][4] = {};

  for (int k0 = 0; k0 < K; k0 += 64) {
    __syncthreads();
#pragma unroll
    for (int p = 0; p < 4; ++p) {
      int rowbase = p * 32 + w * 8;
      GLL(&A[(size_t)(m0 + rowbase + srow) * lda + k0 + sgl * 8], &As[rowbase * 64]);
      GLL(&Bt[(size_t)(n0 + rowbase + srow) * ldb + k0 + sgl * 8], &Bs[rowbase * 64]);
    }
    __syncthreads();
#pragma unroll
    for (int kk = 0; kk < 64; kk += 32) {
      const int kg = kk >> 3;
      const int phys = ((kg + quad) ^ (l15 & 7)) * 8;
      bf16x8 af[4], bfr[4];
#pragma unroll
      for (int mt = 0; mt < 4; ++mt)
        af[mt] = *reinterpret_cast<const bf16x8*>(&As[(wm + mt * 16 + l15) * 64 + phys]);
#pragma unroll
      for (int nt = 0; nt < 4; ++nt)
        bfr[nt] = *reinterpret_cast<const bf16x8*>(&Bs[(wn + nt * 16 + l15) * 64 + phys]);
#pragma unroll
      for (int mt = 0; mt < 4; ++mt)
#pragma unroll
        for (int nt = 0; nt < 4; ++nt)
          acc[mt][nt] = __builtin_amdgcn_mfma_f32_16x16x32_bf16(af[mt], bfr[nt], acc[mt][nt], 0, 0, 0);
    }
  }

  if (TVOUT && n0 >= 2304) {   // V tile -> LDS transpose -> coalesced Vt store
    __syncthreads();           // main-loop LDS reads done before scratch reuse
    const int gg = (n0 - 2304) >> 7;      // block-uniform: 0 or 1
#pragma unroll
    for (int mt = 0; mt < 4; ++mt) {
#pragma unroll
      for (int reg = 0; reg < 4; ++reg) {
        int row = wm + mt * 16 + quad * 4 + reg;
#pragma unroll
        for (int nt = 0; nt < 4; ++nt) {
          int col = wn + nt * 16 + l15;
          S[col * 128 + (row ^ ((col & 31) << 1))] = f2bf(acc[mt][nt][reg]);
        }
      }
    }
    __syncthreads();
    const int bb = m0 >> 11;
    const int tl0 = m0 & 2047;
    const int c2 = t & 63, wv = t >> 6;
#pragma unroll
    for (int p = 0; p < 32; ++p) {
      int dvl = p * 4 + wv;
      int rsw = (2 * c2) ^ ((dvl & 31) << 1);   // even -> {row 2c, row 2c+1} adjacent
      unsigned pair = *reinterpret_cast<const unsigned*>(&S[dvl * 128 + rsw]);
      *reinterpret_cast<unsigned*>(
          &Vt[(size_t)((bb * 2 + gg) * 128 + dvl) * 2048 + tl0 + 2 * c2]) = pair;
    }
    return;
  }

  const float sc = (n0 < nscale) ? scale : 1.0f;
#pragma unroll
  for (int mt = 0; mt < 4; ++mt) {
#pragma unroll
    for (int reg = 0; reg < 4; ++reg) {
      int row = m0 + wm + mt * 16 + quad * 4 + reg;
#pragma unroll
      for (int nt = 0; nt < 4; ++nt) {
        int col = n0 + wn + nt * 16 + l15;
        float v = acc[mt][nt][reg] * sc;
        if (FP32OUT)
          reinterpret_cast<float*>(Cout)[(size_t)row * ldc + col] = v;
        else
          reinterpret_cast<unsigned short*>(Cout)[(size_t)row * ldc + col] = f2bf(v);
      }
    }
  }
}

// ---------- fused causal GQA flash attention, k-parity split (R1-verified) ----------
// grid (2, 8, 32): block (s,bx,bh) handles q-tiles {bx, 15-bx} (128 rows each)
// processing only K/V tiles of parity s -> EXACTLY 17 slots per block.
// T12 in-register softmax (swapped QK^T + cvt_pk + permlane); no setprio.
// R10 delta: BOTH parity partials stored bf16 (fixed-max softmax => additive
// merge tolerates bf16 partials; halves partial write traffic).
#define LDQK 2560
__global__ __launch_bounds__(256, 2) void attn_kernel(const unsigned short* __restrict__ Q,
                                                      const unsigned short* __restrict__ Kg,
                                                      const unsigned short* __restrict__ Vt,
                                                      unsigned short* __restrict__ O0,
                                                      unsigned short* __restrict__ O1,
                                                      float* __restrict__ L) {
  __shared__ __align__(16) unsigned short Ks[2][64 * 128];   // [token][d], swizzled
  __shared__ __align__(16) unsigned short Vs[2][128 * 64];   // [d][token], swizzled

  const int s  = blockIdx.x;            // k-parity
  const int bx = blockIdx.y;            // 0..7
  const int hh = blockIdx.z & 15;
  const int b  = blockIdx.z >> 4;
  const int g  = hh >> 3;
  const int t  = threadIdx.x;
  const int wg = t >> 6, lane = t & 63;
  const int l15 = lane & 15, quad = lane >> 4;

  const unsigned short* Kbase = Kg + (size_t)b * 2048 * LDQK + g * 128;
  const unsigned short* Vbase = Vt + (size_t)(b * 2 + g) * 128 * 2048;

  const int k_r = lane >> 4;
  const int v_r = lane >> 3;

  auto issueK = [&](int tile, unsigned short* dst) {
    const unsigned short* kb = Kbase + (size_t)(tile * 64) * LDQK;
#pragma unroll
    for (int p = 0; p < 4; ++p) {
      int rowbase = p * 16 + wg * 4;
      int row = rowbase + k_r;
      int gl = (lane & 15) ^ (row & 15);
      GLL(&kb[(size_t)row * LDQK + gl * 8], &dst[rowbase * 128]);
    }
  };
  auto issueV = [&](int tile, unsigned short* dst) {
    const unsigned short* vb = Vbase + tile * 64;
#pragma unroll
    for (int p = 0; p < 4; ++p) {
      int rowbase = p * 32 + wg * 8;
      int row = rowbase + v_r;
      int gl = (lane & 7) ^ (row & 7);
      GLL(&vb[(size_t)row * 2048 + gl * 8], &dst[rowbase * 64]);
    }
  };

  int pb = 0;
  issueK(s, Ks[0]);
  issueV(s, Vs[0]);

  for (int ph = 0; ph < 2; ++ph) {
    const int iq = ph ? (15 - bx) : bx;

    bf16x8 qf[2][4];
#pragma unroll
    for (int mi = 0; mi < 2; ++mi) {
      int qrow = iq * 128 + wg * 32 + mi * 16 + l15;
      const unsigned short* qp = &Q[(size_t)(b * 2048 + qrow) * LDQK + hh * 128 + quad * 8];
#pragma unroll
      for (int dk = 0; dk < 4; ++dk)
        qf[mi][dk] = *reinterpret_cast<const bf16x8*>(qp + dk * 32);
    }

    f32x4 o[2][8] = {};
    float l_run[2] = {};

    for (int j = 0; j <= iq; ++j) {
      const int tile = 2 * j + s;
      __syncthreads();   // drains GLLs issued last slot; fences buffer reuse
      const int cur = pb, nxt = pb ^ 1;

      if (j < iq) {
        issueK(tile + 2, Ks[nxt]);
        issueV(tile + 2, Vs[nxt]);
      } else if (ph == 0) {
        issueK(s, Ks[nxt]);
        issueV(s, Vs[nxt]);
      }

      // S^T = K Q^T (swapped operands: row = k-token, col = q-row = l15)
      f32x4 sc[2][4] = {};
#pragma unroll
      for (int nt = 0; nt < 4; ++nt) {
#pragma unroll
        for (int dk = 0; dk < 4; ++dk) {
          int phys = (dk * 4 + quad) ^ l15;
          bf16x8 kf = *reinterpret_cast<const bf16x8*>(&Ks[cur][(nt * 16 + l15) * 128 + phys * 8]);
          sc[0][nt] = __builtin_amdgcn_mfma_f32_16x16x32_bf16(kf, qf[0][dk], sc[0][nt], 0, 0, 0);
          sc[1][nt] = __builtin_amdgcn_mfma_f32_16x16x32_bf16(kf, qf[1][dk], sc[1][nt], 0, 0, 0);
        }
      }
      if (j == iq) {   // last tile of this parity stream: causal mask (S^T indexing)
#pragma unroll
        for (int mi = 0; mi < 2; ++mi)
#pragma unroll
          for (int nt = 0; nt < 4; ++nt) {
#pragma unroll
            for (int reg = 0; reg < 4; ++reg) {
              int kcol = tile * 64 + nt * 16 + quad * 4 + reg;
              int qr = iq * 128 + wg * 32 + mi * 16 + l15;
              if (kcol > qr) sc[mi][nt][reg] = -1e30f;
            }
          }
      }

      // two 32-token halves: softmax + in-register P fragment -> PV
#pragma unroll
      for (int kk = 0; kk < 2; ++kk) {
        bf16x8 pf[2];
#pragma unroll
        for (int mi = 0; mi < 2; ++mi) {
          float pe[4], po[4];
#pragma unroll
          for (int reg = 0; reg < 4; ++reg) {
            pe[reg] = __builtin_exp2f(__builtin_fmaf(sc[mi][kk * 2 + 0][reg], 1.44269504f, -23.08312064f));
            po[reg] = __builtin_exp2f(__builtin_fmaf(sc[mi][kk * 2 + 1][reg], 1.44269504f, -23.08312064f));
            l_run[mi] += pe[reg] + po[reg];
          }
          unsigned a0, a1, b0, b1;
          asm("v_cvt_pk_bf16_f32 %0, %1, %2" : "=v"(a0) : "v"(pe[0]), "v"(pe[1]));
          asm("v_cvt_pk_bf16_f32 %0, %1, %2" : "=v"(a1) : "v"(pe[2]), "v"(pe[3]));
          asm("v_cvt_pk_bf16_f32 %0, %1, %2" : "=v"(b0) : "v"(po[0]), "v"(po[1]));
          asm("v_cvt_pk_bf16_f32 %0, %1, %2" : "=v"(b1) : "v"(po[2]), "v"(po[3]));
          asm("v_permlane32_swap_b32 %0, %1" : "+v"(a0), "+v"(b0));
          asm("v_permlane16_swap_b32 %0, %1" : "+v"(a0), "+v"(b0));
          asm("v_permlane32_swap_b32 %0, %1" : "+v"(a1), "+v"(b1));
          asm("v_permlane16_swap_b32 %0, %1" : "+v"(a1), "+v"(b1));
          u32x4 wd;
          wd[0] = a0;   // tokens q*8+0,1
          wd[1] = a1;   // tokens q*8+2,3
          wd[2] = b0;   // tokens q*8+4,5
          wd[3] = b1;   // tokens q*8+6,7
          pf[mi] = __builtin_bit_cast(bf16x8, wd);
        }
#pragma unroll
        for (int dt = 0; dt < 8; ++dt) {
          int phys = ((kk * 4 + quad) ^ (l15 & 7));
          bf16x8 vf = *reinterpret_cast<const bf16x8*>(&Vs[cur][(dt * 16 + l15) * 64 + phys * 8]);
          o[0][dt] = __builtin_amdgcn_mfma_f32_16x16x32_bf16(pf[0], vf, o[0][dt], 0, 0, 0);
          o[1][dt] = __builtin_amdgcn_mfma_f32_16x16x32_bf16(pf[1], vf, o[1][dt], 0, 0, 0);
        }
      }
      pb ^= 1;
    }

    // l lives per (qrow=l15, quad-partial): reduce across quads
#pragma unroll
    for (int mi = 0; mi < 2; ++mi) {
      l_run[mi] += __shfl_xor(l_run[mi], 16);
      l_run[mi] += __shfl_xor(l_run[mi], 32);
    }

    unsigned short* Op = (s == 0) ? O0 : O1;
#pragma unroll
    for (int mi = 0; mi < 2; ++mi) {
      if (quad == 0) {
        int lrow = wg * 32 + mi * 16 + l15;
        L[(size_t)s * 65536 + (size_t)(b * 2048 + iq * 128 + lrow) * 16 + hh] = l_run[mi];
      }
#pragma unroll
      for (int reg = 0; reg < 4; ++reg) {
        int row = wg * 32 + mi * 16 + quad * 4 + reg;
        size_t base = (size_t)(b * 2048 + iq * 128 + row) * 2048 + hh * 128;
#pragma unroll
        for (int dt = 0; dt < 8; ++dt)
          Op[base + dt * 16 + l15] = f2bf(o[mi][dt][reg]);
      }
    }
  }
}

// ---------- merge: Y = (O0 + O1) / (l0 + l1), bf16, in-place over O1 ----------
__global__ __launch_bounds__(256) void merge_kernel(const unsigned short* __restrict__ O0,
                                                    unsigned short* __restrict__ O1,
                                                    const float* __restrict__ L) {
  int i4 = blockIdx.x * 256 + threadIdx.x;   // 0..2097151, 4 elems each
  int e = i4 << 2;
  int tr = e >> 11;              // token row 0..4095
  int hh = (e >> 7) & 15;        // head
  float l = L[tr * 16 + hh] + L[65536 + tr * 16 + hh];
  float inv = 1.0f / l;
  ushort4 a = reinterpret_cast<const ushort4*>(O0)[i4];
  ushort4 u = reinterpret_cast<const ushort4*>(O1)[i4];
  ushort4 r;
  r.x = f2bf((bf2f(a.x) + bf2f(u.x)) * inv);
  r.y = f2bf((bf2f(a.y) + bf2f(u.y)) * inv);
  r.z = f2bf((bf2f(a.z) + bf2f(u.z)) * inv);
  r.w = f2bf((bf2f(a.w) + bf2f(u.w)) * inv);
  reinterpret_cast<ushort4*>(O1)[i4] = r;
}

extern "C" void kernel_launch(void* const* d_in, const int* in_sizes, int n_in,
                              void* d_out, int out_size, void* d_ws, size_t ws_size,
                              hipStream_t stream) {
  const float* x  = (const float*)d_in[0];
  const float* Wq = (const float*)d_in[1];
  const float* Wk = (const float*)d_in[2];
  const float* Wv = (const float*)d_in[3];
  const float* Wo = (const float*)d_in[4];

  char* ws = (char*)d_ws;
  unsigned short* xb    = (unsigned short*)(ws + 0);          // 16 MB (reused: O1/Y)
  unsigned short* Wqkvt = (unsigned short*)(ws + 16777216);   // 10.5 MB
  unsigned short* Wot   = (unsigned short*)(ws + 27262976);   // 8 MB
  unsigned short* QKVb  = (unsigned short*)(ws + 35651584);   // 20 MB
  unsigned short* Vtb   = (unsigned short*)(ws + 56623104);   // 2 MB
  float*          Lb    = (float*)(ws + 58720256);            // 512 KB: [2][4096][16]
  unsigned short* Yb    = xb;
  unsigned short* O0b   = (unsigned short*)d_out;             // 16 MB bf16 scratch in out buffer

  prep_kernel<<<10496, 256, 0, stream>>>(x, Wq, Wk, Wv, Wo, xb, Wqkvt, Wot);

  const float qscale = 0.08838834764831845f;  // 1/sqrt(128), folded into Q
  // QKV projection; V column-blocks go through LDS transpose into Vtb (tv fused)
  gemm_bt_kernel<false, true><<<dim3(32, 20), 256, 0, stream>>>(xb, Wqkvt, QKVb, Vtb,
                                                                2048, 2048, 2048, 2560,
                                                                qscale, 2048);
  // attention partials: both parities bf16 (O0 -> d_out scratch, O1 -> xb)
  attn_kernel<<<dim3(2, 8, 32), 256, 0, stream>>>(QKVb, QKVb + 2048, Vtb,
                                                  O0b, Yb, Lb);
  merge_kernel<<<8192, 256, 0, stream>>>(O0b, Yb, Lb);
  gemm_bt_kernel<true, false><<<dim3(32, 16), 256, 0, stream>>>(Yb, Wot, d_out, nullptr,
                                                                2048, 2048, 2048, 2048,
                                                                1.0f, 0);
}